// Round 4
// baseline (16885.583 us; speedup 1.0000x reference)
//
#include <hip/hip_runtime.h>

// STA-LSTM forward: B=2048, S=128, D=64, H1=H2=128, OUT=1
// Kernel A (256 blk x 1024 thr, 1 blk/CU via 84KB LDS, 4 waves/SIMD):
//   phase 1: spatial-attn LSTM (16-wave k-sliced attention, k-split gate GEMM)
//   phase 2: betas + h_att (overwrites H in ws)
// Kernel B (8192 blk x 512 thr): G0 = h_att @ ta_W + ta_b  (non-recurrent hoist)
// Kernel C (256 blk x 1024 thr, 1 blk/CU): temporal LSTM; G0 path or direct fallback.

#define BB 2048
#define SS 128
#define DD 64
#define HH 128
#define NG 512
#define M  8
#define NT 1024

#define A_OFF    ((size_t)BB)
#define BETA_OFF ((size_t)BB + (size_t)SS*BB*DD)
#define G0_BYTES ((size_t)BB*SS*NG*4)
#define H_BYTES  ((size_t)BB*SS*HH*4)

__device__ __forceinline__ float sigf(float x){ return 1.0f/(1.0f + __expf(-x)); }
__device__ __forceinline__ float tanhx(float x){ return 1.0f - 2.0f/(1.0f + __expf(2.0f*x)); }

__device__ __forceinline__ float wmax64(float v){
#pragma unroll
  for (int m = 32; m; m >>= 1) v = fmaxf(v, __shfl_xor(v, m, 64));
  return v;
}
__device__ __forceinline__ float wsum64(float v){
#pragma unroll
  for (int m = 32; m; m >>= 1) v += __shfl_xor(v, m, 64);
  return v;
}

struct SM1 {                       // 14 KB
  float x[M][DD];
  float h[M][HH];
  float c[M][HH];
  float a[M][DD];
  float xw[M][DD];
};
struct PH1 { SM1 s; float red[8192]; };   // 14K + 32K = 46 KB
struct SM2 {                       // 48 KB
  float A[32][HH];
  float tmp[32][SS];
  float bp[32][SS];
};
// pad forces sizeof(union)=84KB -> exactly 1 block/CU (160KB LDS pool)
union __align__(16) SMA { PH1 p1; SM2 p2; float pad[21504]; };

__global__ __launch_bounds__(NT, 4) void sta_ph12_kernel(
    const float* __restrict__ X,
    const float* __restrict__ saW,  const float* __restrict__ saU,  const float* __restrict__ sab,
    const float* __restrict__ saWa, const float* __restrict__ saUa, const float* __restrict__ saba,
    const float* __restrict__ saVa,
    const float* __restrict__ taWa, const float* __restrict__ taba, const float* __restrict__ taVa,
    float* __restrict__ out, float* __restrict__ Hws)
{
  __shared__ SMA sm;
  const int tid = threadIdx.x;
  const int b0  = blockIdx.x * M;
  const int w   = tid >> 6;      // wave 0..15
  const int l   = tid & 63;      // lane

  // ================= Phase 1: spatial-attention LSTM =================
  if (tid < M*HH){
    int r = tid >> 7, j = tid & 127;
    sm.p1.s.h[r][j] = 0.f; sm.p1.s.c[r][j] = 0.f;
  }
  if (tid < 512){ // stage x_0
    int r = tid >> 6, d = tid & 63;
    sm.p1.s.x[r][d] = X[(size_t)(b0+r)*SS*DD + d];
  }
  __syncthreads();

  for (int t = 0; t < SS; ++t){
    // ---- attn GEMM1 partials: a_pre = x@saWa + [h,c]@saUa ----
    // wave w: x rows [w*4,w*4+4), h rows [w*8,+8), c rows [w*8,+8)
    {
      float pr[M];
#pragma unroll
      for (int r = 0; r < M; ++r) pr[r] = 0.f;
      { // x part: 1 k-block
        const int k = w*4;
        const float* wp = saWa + (size_t)k*DD + l;
        float w0 = wp[0], w1 = wp[DD], w2 = wp[2*DD], w3 = wp[3*DD];
#pragma unroll
        for (int r = 0; r < M; ++r){
          float4 v = *(const float4*)&sm.p1.s.x[r][k];
          pr[r] += w0*v.x + w1*v.y + w2*v.z + w3*v.w;
        }
      }
#pragma unroll
      for (int q = 0; q < 2; ++q){ // h part: 2 k-blocks
        const int k = w*8 + q*4;
        const float* wp = saUa + (size_t)k*DD + l;
        float w0 = wp[0], w1 = wp[DD], w2 = wp[2*DD], w3 = wp[3*DD];
#pragma unroll
        for (int r = 0; r < M; ++r){
          float4 v = *(const float4*)&sm.p1.s.h[r][k];
          pr[r] += w0*v.x + w1*v.y + w2*v.z + w3*v.w;
        }
      }
#pragma unroll
      for (int q = 0; q < 2; ++q){ // c part: 2 k-blocks (saUa rows HH..2HH)
        const int k = w*8 + q*4;
        const float* wp = saUa + (size_t)(HH + k)*DD + l;
        float w0 = wp[0], w1 = wp[DD], w2 = wp[2*DD], w3 = wp[3*DD];
#pragma unroll
        for (int r = 0; r < M; ++r){
          float4 v = *(const float4*)&sm.p1.s.c[r][k];
          pr[r] += w0*v.x + w1*v.y + w2*v.z + w3*v.w;
        }
      }
#pragma unroll
      for (int r = 0; r < M; ++r) sm.p1.red[w*512 + r*64 + l] = pr[r];
    }
    __syncthreads();

    // ---- reduce1 + bias + tanh -> a ----
    if (tid < 512){
      const int r = tid >> 6, col = tid & 63;
      float s0 = saba[col], s1 = 0.f;
#pragma unroll
      for (int u = 0; u < 16; u += 2){
        s0 += sm.p1.red[u*512     + r*64 + col];
        s1 += sm.p1.red[(u+1)*512 + r*64 + col];
      }
      sm.p1.s.a[r][col] = tanhx(s0 + s1);
    }
    __syncthreads();

    // ---- attn GEMM2 partials: av = a @ saVa (wave w: k-block at w*4) ----
    {
      float pr[M];
#pragma unroll
      for (int r = 0; r < M; ++r) pr[r] = 0.f;
      const int k = w*4;
      const float* wp = saVa + (size_t)k*DD + l;
      float w0 = wp[0], w1 = wp[DD], w2 = wp[2*DD], w3 = wp[3*DD];
#pragma unroll
      for (int r = 0; r < M; ++r){
        float4 v = *(const float4*)&sm.p1.s.a[r][k];
        pr[r] += w0*v.x + w1*v.y + w2*v.z + w3*v.w;
      }
#pragma unroll
      for (int r = 0; r < M; ++r) sm.p1.red[w*512 + r*64 + l] = pr[r];
    }
    __syncthreads();

    // ---- reduce2 + softmax + alphas out + xw ----
    if (tid < 512){
      const int r = tid >> 6, col = tid & 63;
      float s0 = 0.f, s1 = 0.f;
#pragma unroll
      for (int u = 0; u < 16; u += 2){
        s0 += sm.p1.red[u*512     + r*64 + col];
        s1 += sm.p1.red[(u+1)*512 + r*64 + col];
      }
      float s = s0 + s1;
      float mm = wmax64(s);
      float e  = __expf(s - mm);
      float al = e * (1.0f / wsum64(e));
      out[A_OFF + (size_t)t*BB*DD + (size_t)(b0+r)*DD + col] = al;
      sm.p1.s.xw[r][col] = al * sm.p1.s.x[r][col];
    }
    __syncthreads();

    // ---- gates partials: xw@saW + h@saU + sab, K split across 2 threads/col ----
    {
      const int c    = tid & 511;
      const int half = tid >> 9;           // wave-uniform
      float acc[M];
      if (half == 0){
        const float bv = sab[c];
#pragma unroll
        for (int r = 0; r < M; ++r) acc[r] = bv;
        for (int k = 0; k < DD; k += 4){   // xw part, k 0..63
          const float* wp = saW + (size_t)k*NG + c;
          float w0 = wp[0], w1 = wp[NG], w2 = wp[2*NG], w3 = wp[3*NG];
#pragma unroll
          for (int r = 0; r < M; ++r){
            float4 v = *(const float4*)&sm.p1.s.xw[r][k];
            acc[r] += w0*v.x + w1*v.y + w2*v.z + w3*v.w;
          }
        }
        for (int k = 0; k < 32; k += 4){   // h part, k 0..31
          const float* wp = saU + (size_t)k*NG + c;
          float w0 = wp[0], w1 = wp[NG], w2 = wp[2*NG], w3 = wp[3*NG];
#pragma unroll
          for (int r = 0; r < M; ++r){
            float4 v = *(const float4*)&sm.p1.s.h[r][k];
            acc[r] += w0*v.x + w1*v.y + w2*v.z + w3*v.w;
          }
        }
      } else {
#pragma unroll
        for (int r = 0; r < M; ++r) acc[r] = 0.f;
        for (int k = 32; k < HH; k += 4){  // h part, k 32..127
          const float* wp = saU + (size_t)k*NG + c;
          float w0 = wp[0], w1 = wp[NG], w2 = wp[2*NG], w3 = wp[3*NG];
#pragma unroll
          for (int r = 0; r < M; ++r){
            float4 v = *(const float4*)&sm.p1.s.h[r][k];
            acc[r] += w0*v.x + w1*v.y + w2*v.z + w3*v.w;
          }
        }
      }
#pragma unroll
      for (int r = 0; r < M; ++r) sm.p1.red[half*4096 + r*512 + c] = acc[r];
    }
    __syncthreads();

    // ---- combine halves + LSTM pointwise + store H + stage x_{t+1} ----
    {
      const int r = tid >> 7, j = tid & 127;
      float g0 = sm.p1.red[r*512 + j      ] + sm.p1.red[4096 + r*512 + j      ];
      float g1 = sm.p1.red[r*512 + j + 128] + sm.p1.red[4096 + r*512 + j + 128];
      float g2 = sm.p1.red[r*512 + j + 256] + sm.p1.red[4096 + r*512 + j + 256];
      float g3 = sm.p1.red[r*512 + j + 384] + sm.p1.red[4096 + r*512 + j + 384];
      float iv = sigf(g0), fv = sigf(g1), gv = tanhx(g2), ov = sigf(g3);
      float cn = fv * sm.p1.s.c[r][j] + iv * gv;
      float hn = ov * tanhx(cn);
      sm.p1.s.c[r][j] = cn; sm.p1.s.h[r][j] = hn;
      Hws[(size_t)(b0+r)*SS*HH + (size_t)t*HH + j] = hn;
    }
    if (t + 1 < SS && tid < 512){
      int r = tid >> 6, d = tid & 63;
      sm.p1.s.x[r][d] = X[(size_t)(b0+r)*SS*DD + (size_t)(t+1)*DD + d];
    }
    __syncthreads();
  }

  // ================= Phase 2: betas + h_att (overwrites H in-place) =================
  for (int r = 0; r < M; ++r){
    float* Hrow = Hws + (size_t)(b0+r)*SS*HH;
    const int c  = tid & 127;
    const int th = tid >> 7;   // 0..7, owns rows th*4..th*4+3 of each 32-row chunk
    float hacc[16];
#pragma unroll
    for (int i = 0; i < 16; ++i) hacc[i] = 0.f;

#pragma unroll
    for (int ch = 0; ch < 4; ++ch){
      // stage 32 H rows (16 KB), 1 float4/thread
      ((float4*)sm.p2.A)[tid] = ((const float4*)(Hrow + (size_t)ch*32*HH))[tid];
      __syncthreads();

      { // GEMM1: tmp = tanh(A @ taWa + taba)
        float acc[4];
        const float bv = taba[c];
#pragma unroll
        for (int i = 0; i < 4; ++i) acc[i] = bv;
        for (int k = 0; k < HH; k += 4){
          const float* wp = taWa + (size_t)k*SS + c;
          float w0 = wp[0], w1 = wp[SS], w2 = wp[2*SS], w3 = wp[3*SS];
#pragma unroll
          for (int i = 0; i < 4; ++i){
            float4 v = *(const float4*)&sm.p2.A[th*4+i][k];
            acc[i] += w0*v.x + w1*v.y + w2*v.z + w3*v.w;
          }
        }
#pragma unroll
        for (int i = 0; i < 4; ++i) sm.p2.tmp[th*4+i][c] = tanhx(acc[i]);
      }
      __syncthreads();

      { // GEMM2: bp = tmp @ taVa
        float acc[4];
#pragma unroll
        for (int i = 0; i < 4; ++i) acc[i] = 0.f;
        for (int k = 0; k < SS; k += 4){
          const float* wp = taVa + (size_t)k*SS + c;
          float w0 = wp[0], w1 = wp[SS], w2 = wp[2*SS], w3 = wp[3*SS];
#pragma unroll
          for (int i = 0; i < 4; ++i){
            float4 v = *(const float4*)&sm.p2.tmp[th*4+i][k];
            acc[i] += w0*v.x + w1*v.y + w2*v.z + w3*v.w;
          }
        }
#pragma unroll
        for (int i = 0; i < 4; ++i) sm.p2.bp[th*4+i][c] = acc[i];
      }
      __syncthreads();

      { // softmax rows of bp -> beta ; write betas ; keep beta in LDS
        const int wv = tid >> 6, lane = tid & 63;
#pragma unroll
        for (int it = 0; it < 2; ++it){
          int tl = wv + 16*it;
          float v0 = sm.p2.bp[tl][lane], v1 = sm.p2.bp[tl][lane+64];
          float mm = wmax64(fmaxf(v0, v1));
          float e0 = __expf(v0 - mm), e1 = __expf(v1 - mm);
          float inv = 1.0f / wsum64(e0 + e1);
          e0 *= inv; e1 *= inv;
          size_t bo = BETA_OFF + (size_t)(ch*32+tl)*BB*SS + (size_t)(b0+r)*SS;
          out[bo + lane]      = e0;
          out[bo + lane + 64] = e1;
          sm.p2.bp[tl][lane]      = e0;
          sm.p2.bp[tl][lane + 64] = e1;
        }
      }
      __syncthreads();

      // GEMM3: h_att(chunk rows) += beta @ Hrow
      for (int k = 0; k < SS; k += 4){
        const float* hp = Hrow + (size_t)k*HH + c;
        float hv0 = hp[0], hv1 = hp[HH], hv2 = hp[2*HH], hv3 = hp[3*HH];
#pragma unroll
        for (int i = 0; i < 4; ++i){
          float4 bv = *(const float4*)&sm.p2.bp[th*4+i][k];
          hacc[ch*4+i] += bv.x*hv0 + bv.y*hv1 + bv.z*hv2 + bv.w*hv3;
        }
      }
    }
    __syncthreads();   // all Hrow reads complete before overwrite
#pragma unroll
    for (int ch = 0; ch < 4; ++ch)
#pragma unroll
      for (int i = 0; i < 4; ++i)
        Hrow[(size_t)(ch*32 + th*4 + i)*HH + c] = hacc[ch*4+i];
    __syncthreads();
  }
}

// ============ Kernel B: G0[b,t,:] = h_att[b,t,:] @ ta_W + ta_b ============
#define BROWS 32
#define NTB 512
__global__ __launch_bounds__(NTB, 2) void g0_kernel(
    const float* __restrict__ Ha, const float* __restrict__ taW,
    const float* __restrict__ tab, float* __restrict__ G0)
{
  __shared__ float hs[BROWS][HH];   // 16 KB
  const int tid = threadIdx.x;
  const size_t row0 = (size_t)blockIdx.x * BROWS;
  for (int idx = tid; idx < BROWS*HH/4; idx += NTB)
    ((float4*)hs)[idx] = ((const float4*)(Ha + row0*HH))[idx];
  __syncthreads();
  const int c = tid;
  float acc[BROWS];
  const float tb = tab[c];
#pragma unroll
  for (int r = 0; r < BROWS; ++r) acc[r] = tb;
  for (int k = 0; k < HH; k += 4){
    const float* wp = taW + (size_t)k*NG + c;
    float w0 = wp[0], w1 = wp[NG], w2 = wp[2*NG], w3 = wp[3*NG];
#pragma unroll
    for (int r = 0; r < BROWS; ++r){
      float4 v = *(const float4*)&hs[r][k];
      acc[r] += w0*v.x + w1*v.y + w2*v.z + w3*v.w;
    }
  }
#pragma unroll
  for (int r = 0; r < BROWS; ++r) G0[(row0 + r)*NG + c] = acc[r];
}

// ============ Kernel C: temporal LSTM ============
union __align__(16) SMC {
  struct {
    float ha[M][HH];
    float lh[M][HH];
    float lc[M][HH];
    float yp[M];
    float red[8192];
  } s;
  float pad[21504];   // force 84KB -> 1 block/CU
};

template<int UG>
__global__ __launch_bounds__(NT, 4) void sta_ph3_kernel(
    const float* __restrict__ X, const float* __restrict__ Ha,
    const float* __restrict__ G0,
    const float* __restrict__ taW, const float* __restrict__ taU,
    const float* __restrict__ tab, const float* __restrict__ taWy,
    const float* __restrict__ fcw, const float* __restrict__ fcb,
    float* __restrict__ out)
{
  __shared__ SMC sm;
  const int tid = threadIdx.x;
  const int b0  = blockIdx.x * M;

  if (tid < M*HH){
    int r = tid >> 7, j = tid & 127;
    sm.s.lh[r][j] = 0.f; sm.s.lc[r][j] = 0.f;
  }
  if (tid < M) sm.s.yp[tid] = X[(size_t)(b0+tid)*SS*DD + (DD-1)];
  if (!UG && tid < M*HH/4){
    int r = tid >> 5, q = tid & 31;
    ((float4*)sm.s.ha)[tid] = *(const float4*)(Ha + (size_t)(b0+r)*SS*HH + q*4);
  }
  __syncthreads();

  for (int t = 0; t < SS; ++t){
    // ---- gates partials (K split across 2 threads/col) ----
    {
      const int c    = tid & 511;
      const int half = tid >> 9;           // wave-uniform
      float acc[M];
      if (UG){
        if (half == 0){
          const float wy = taWy[c];
#pragma unroll
          for (int r = 0; r < M; ++r) acc[r] = sm.s.yp[r]*wy;
          for (int k = 0; k < 64; k += 4){
            const float* wp = taU + (size_t)k*NG + c;
            float w0 = wp[0], w1 = wp[NG], w2 = wp[2*NG], w3 = wp[3*NG];
#pragma unroll
            for (int r = 0; r < M; ++r){
              float4 v = *(const float4*)&sm.s.lh[r][k];
              acc[r] += w0*v.x + w1*v.y + w2*v.z + w3*v.w;
            }
          }
        } else {
          float g0v[M];
#pragma unroll
          for (int r = 0; r < M; ++r)
            g0v[r] = G0[((size_t)(b0+r)*SS + t)*NG + c];
          for (int k = 64; k < HH; k += 4){
            const float* wp = taU + (size_t)k*NG + c;
            float w0 = wp[0], w1 = wp[NG], w2 = wp[2*NG], w3 = wp[3*NG];
#pragma unroll
            for (int r = 0; r < M; ++r){
              float4 v = *(const float4*)&sm.s.lh[r][k];
              g0v[r] += w0*v.x + w1*v.y + w2*v.z + w3*v.w;
            }
          }
#pragma unroll
          for (int r = 0; r < M; ++r) acc[r] = g0v[r];
        }
      } else {
        if (half == 0){
          const float wy = taWy[c];
          const float tb = tab[c];
#pragma unroll
          for (int r = 0; r < M; ++r) acc[r] = tb + sm.s.yp[r]*wy;
        } else {
#pragma unroll
          for (int r = 0; r < M; ++r) acc[r] = 0.f;
        }
        const int k0 = half*64;
        for (int k = k0; k < k0+64; k += 4){
          const float* wpW = taW + (size_t)k*NG + c;
          const float* wpU = taU + (size_t)k*NG + c;
          float a0 = wpW[0], a1 = wpW[NG], a2 = wpW[2*NG], a3 = wpW[3*NG];
          float u0 = wpU[0], u1 = wpU[NG], u2 = wpU[2*NG], u3 = wpU[3*NG];
#pragma unroll
          for (int r = 0; r < M; ++r){
            float4 vh = *(const float4*)&sm.s.ha[r][k];
            float4 vl = *(const float4*)&sm.s.lh[r][k];
            acc[r] += a0*vh.x + a1*vh.y + a2*vh.z + a3*vh.w
                    + u0*vl.x + u1*vl.y + u2*vl.z + u3*vl.w;
          }
        }
      }
#pragma unroll
      for (int r = 0; r < M; ++r) sm.s.red[half*4096 + r*512 + c] = acc[r];
    }
    __syncthreads();

    // ---- combine + pointwise + (fallback) stage ha(t+1) ----
    {
      const int r = tid >> 7, j = tid & 127;
      float g0 = sm.s.red[r*512 + j      ] + sm.s.red[4096 + r*512 + j      ];
      float g1 = sm.s.red[r*512 + j + 128] + sm.s.red[4096 + r*512 + j + 128];
      float g2 = sm.s.red[r*512 + j + 256] + sm.s.red[4096 + r*512 + j + 256];
      float g3 = sm.s.red[r*512 + j + 384] + sm.s.red[4096 + r*512 + j + 384];
      float iv = sigf(g0), fv = sigf(g1), gv = tanhx(g2), ov = sigf(g3);
      float cn = fv * sm.s.lc[r][j] + iv * gv;
      float hn = ov * tanhx(cn);
      sm.s.lc[r][j] = cn; sm.s.lh[r][j] = hn;
    }
    if (!UG && t + 1 < SS && tid < M*HH/4){
      int r = tid >> 5, q = tid & 31;
      ((float4*)sm.s.ha)[tid] =
        *(const float4*)(Ha + (size_t)(b0+r)*SS*HH + (size_t)(t+1)*HH + q*4);
    }
    __syncthreads();

    // ---- y = lh @ fc_w^T + fc_b (wave r, 64 lanes) ----
    if (tid < 512){
      const int r = tid >> 6, l = tid & 63;
      float p = sm.s.lh[r][l] * fcw[l] + sm.s.lh[r][l+64] * fcw[l+64];
      p = wsum64(p);
      if (l == 0) sm.s.yp[r] = p + fcb[0];
    }
    __syncthreads();
  }

  if (tid < M) out[b0 + tid] = sm.s.yp[tid];
}

extern "C" void kernel_launch(void* const* d_in, const int* in_sizes, int n_in,
                              void* d_out, int out_size, void* d_ws, size_t ws_size,
                              hipStream_t stream) {
  (void)in_sizes; (void)n_in; (void)out_size;
  const float* X    = (const float*)d_in[0];
  const float* saW  = (const float*)d_in[1];
  const float* saU  = (const float*)d_in[2];
  const float* sab  = (const float*)d_in[3];
  const float* saWa = (const float*)d_in[4];
  const float* saUa = (const float*)d_in[5];
  const float* saba = (const float*)d_in[6];
  const float* saVa = (const float*)d_in[7];
  const float* taWa = (const float*)d_in[8];
  // d_in[9] = ta_Ua: unused by the reference forward pass
  const float* taba = (const float*)d_in[10];
  const float* taVa = (const float*)d_in[11];
  const float* taW  = (const float*)d_in[12];
  const float* taU  = (const float*)d_in[13];
  const float* tab  = (const float*)d_in[14];
  const float* taWy = (const float*)d_in[15];
  const float* fcw  = (const float*)d_in[16];
  const float* fcb  = (const float*)d_in[17];
  float* out = (float*)d_out;
  float* Hws = (float*)d_ws;                       // B*S*H floats: H, then h_att
  float* G0  = Hws + (size_t)BB*SS*HH;             // B*S*4H2 floats (if ws allows)
  const bool useG0 = ws_size >= (H_BYTES + G0_BYTES);

  hipLaunchKernelGGL(sta_ph12_kernel, dim3(BB / M), dim3(NT), 0, stream,
                     X, saW, saU, sab, saWa, saUa, saba, saVa,
                     taWa, taba, taVa, out, Hws);
  if (useG0){
    hipLaunchKernelGGL(g0_kernel, dim3((BB*SS)/BROWS), dim3(NTB), 0, stream,
                       Hws, taW, tab, G0);
    hipLaunchKernelGGL((sta_ph3_kernel<1>), dim3(BB / M), dim3(NT), 0, stream,
                       X, Hws, G0, taW, taU, tab, taWy, fcw, fcb, out);
  } else {
    hipLaunchKernelGGL((sta_ph3_kernel<0>), dim3(BB / M), dim3(NT), 0, stream,
                       X, Hws, G0, taW, taU, tab, taWy, fcw, fcb, out);
  }
}

// Round 5
// 6759.040 us; speedup vs baseline: 2.4982x; 2.4982x over previous
//
#include <hip/hip_runtime.h>

// STA-LSTM forward: B=2048, S=128, D=64, H1=H2=128, OUT=1
// Weight-stationary design:
//   Kernel A (256 blk x 512 thr, 1 blk/CU via 144KB LDS, 2 waves/SIMD pinned):
//     phase 1: spatial-attn LSTM. Gate weights (192 f/thread) in REGISTERS,
//              attention weights (96KB) in LDS. 4 barriers/step.
//     phase 2: betas + h_att (overwrites H in ws)
//   Kernel B (8192 blk x 512 thr): G0 = h_att @ ta_W + ta_b
//   Kernel C (256 blk x 512 thr): temporal LSTM, taU (128 f/thread) in registers.

#define BB 2048
#define SS 128
#define DD 64
#define HH 128
#define NG 512
#define M  8
#define NT 512

#define A_OFF    ((size_t)BB)
#define BETA_OFF ((size_t)BB + (size_t)SS*BB*DD)
#define G0_BYTES ((size_t)BB*SS*NG*4)
#define H_BYTES  ((size_t)BB*SS*HH*4)

// attention-weight LDS offsets (floats)
#define AW_WA 0
#define AW_UA (64*64)
#define AW_VA (64*64 + 256*64)
#define AW_TOT (64*64 + 256*64 + 64*64)   // 24576 floats = 96KB

__device__ __forceinline__ float sigf(float x){ return 1.0f/(1.0f + __expf(-x)); }
__device__ __forceinline__ float tanhx(float x){ return 1.0f - 2.0f/(1.0f + __expf(2.0f*x)); }

__device__ __forceinline__ float wmax64(float v){
#pragma unroll
  for (int m = 32; m; m >>= 1) v = fmaxf(v, __shfl_xor(v, m, 64));
  return v;
}
__device__ __forceinline__ float wsum64(float v){
#pragma unroll
  for (int m = 32; m; m >>= 1) v += __shfl_xor(v, m, 64);
  return v;
}

struct P1 {                        // 44 KB
  float x[M][DD];
  float h[M][HH];
  float c[M][HH];
  float xw[M][DD];
  float g[M][NG];
  float red[8][512];
};
struct P2 {                        // 48 KB
  float A[32][HH];
  float tmp[32][SS];
  float bp[32][SS];
};
union __align__(16) SMU { P1 p1; P2 p2; };

__global__ __launch_bounds__(NT) __attribute__((amdgpu_waves_per_eu(2, 2)))
void sta_ph12_kernel(
    const float* __restrict__ X,
    const float* __restrict__ saW,  const float* __restrict__ saU,  const float* __restrict__ sab,
    const float* __restrict__ saWa, const float* __restrict__ saUa, const float* __restrict__ saba,
    const float* __restrict__ saVa,
    const float* __restrict__ taWa, const float* __restrict__ taba, const float* __restrict__ taVa,
    float* __restrict__ out, float* __restrict__ Hws)
{
  __shared__ SMU sm;
  __shared__ float aw[AW_TOT];     // 96 KB attn weights; total LDS 144KB -> 1 blk/CU
  const int tid = threadIdx.x;
  const int b0  = blockIdx.x * M;
  const int w   = tid >> 6;        // wave 0..7
  const int l   = tid & 63;        // lane

  // ---- one-time: attention weights -> LDS ----
  for (int i = tid; i < 1024; i += NT) ((float4*)&aw[AW_WA])[i] = ((const float4*)saWa)[i];
  for (int i = tid; i < 4096; i += NT) ((float4*)&aw[AW_UA])[i] = ((const float4*)saUa)[i];
  for (int i = tid; i < 1024; i += NT) ((float4*)&aw[AW_VA])[i] = ((const float4*)saVa)[i];

  // ---- one-time: gate weights -> registers (192 VGPR, static indexing only) ----
  float wW[DD], wU[HH];
#pragma unroll
  for (int k = 0; k < DD; ++k) wW[k] = saW[(size_t)k*NG + tid];
#pragma unroll
  for (int k = 0; k < HH; ++k) wU[k] = saU[(size_t)k*NG + tid];
  const float gbv = sab[tid];

  // init h,c and stage x_0
  for (int idx = tid; idx < M*HH; idx += NT){
    int r = idx >> 7, j = idx & 127;
    sm.p1.h[r][j] = 0.f; sm.p1.c[r][j] = 0.f;
  }
  { int r = tid >> 6, d = tid & 63;
    sm.p1.x[r][d] = X[(size_t)(b0+r)*SS*DD + d]; }
  __syncthreads();

  // ================= Phase 1 t-loop (4 barriers/step) =================
  for (int t = 0; t < SS; ++t){
    // ---- attn GEMM1 partials (wave k-slices, weights from LDS) ----
    {
      float pr[M];
#pragma unroll
      for (int r = 0; r < M; ++r) pr[r] = 0.f;
#pragma unroll
      for (int q = 0; q < 2; ++q){            // x part: k in [w*8, w*8+8)
        const int k = w*8 + q*4;
        float w0 = aw[AW_WA + (k+0)*64 + l], w1 = aw[AW_WA + (k+1)*64 + l];
        float w2 = aw[AW_WA + (k+2)*64 + l], w3 = aw[AW_WA + (k+3)*64 + l];
#pragma unroll
        for (int r = 0; r < M; ++r){
          float4 v = *(const float4*)&sm.p1.x[r][k];
          pr[r] += w0*v.x + w1*v.y + w2*v.z + w3*v.w;
        }
      }
#pragma unroll
      for (int q = 0; q < 4; ++q){            // h part: k in [w*16, w*16+16)
        const int k = w*16 + q*4;
        float w0 = aw[AW_UA + (k+0)*64 + l], w1 = aw[AW_UA + (k+1)*64 + l];
        float w2 = aw[AW_UA + (k+2)*64 + l], w3 = aw[AW_UA + (k+3)*64 + l];
#pragma unroll
        for (int r = 0; r < M; ++r){
          float4 v = *(const float4*)&sm.p1.h[r][k];
          pr[r] += w0*v.x + w1*v.y + w2*v.z + w3*v.w;
        }
      }
#pragma unroll
      for (int q = 0; q < 4; ++q){            // c part: saUa rows HH+k
        const int k = w*16 + q*4;
        float w0 = aw[AW_UA + (HH+k+0)*64 + l], w1 = aw[AW_UA + (HH+k+1)*64 + l];
        float w2 = aw[AW_UA + (HH+k+2)*64 + l], w3 = aw[AW_UA + (HH+k+3)*64 + l];
#pragma unroll
        for (int r = 0; r < M; ++r){
          float4 v = *(const float4*)&sm.p1.c[r][k];
          pr[r] += w0*v.x + w1*v.y + w2*v.z + w3*v.w;
        }
      }
#pragma unroll
      for (int r = 0; r < M; ++r) sm.p1.red[w][r*64 + l] = pr[r];
    }
    __syncthreads();

    // ---- wave r: reduce + tanh + attn2 (shuffle) + softmax + xw ----
    {
      const int r = w;
      float s = saba[l];
#pragma unroll
      for (int u = 0; u < 8; ++u) s += sm.p1.red[u][r*64 + l];
      float a_rl = tanhx(s);
      float av = 0.f;
#pragma unroll
      for (int k = 0; k < 64; ++k)
        av += __shfl(a_rl, k, 64) * aw[AW_VA + k*64 + l];
      float mm = wmax64(av);
      float e  = __expf(av - mm);
      float al = e * (1.0f / wsum64(e));
      out[A_OFF + (size_t)t*BB*DD + (size_t)(b0+r)*DD + l] = al;
      sm.p1.xw[r][l] = al * sm.p1.x[r][l];
    }
    __syncthreads();

    // ---- gates: weight-stationary, pure LDS-broadcast + FMA ----
    {
      float acc[M];
#pragma unroll
      for (int r = 0; r < M; ++r) acc[r] = gbv;
#pragma unroll
      for (int kb = 0; kb < DD; kb += 4){
#pragma unroll
        for (int r = 0; r < M; ++r){
          float4 v = *(const float4*)&sm.p1.xw[r][kb];
          acc[r] += wW[kb]*v.x + wW[kb+1]*v.y + wW[kb+2]*v.z + wW[kb+3]*v.w;
        }
      }
#pragma unroll
      for (int kb = 0; kb < HH; kb += 4){
#pragma unroll
        for (int r = 0; r < M; ++r){
          float4 v = *(const float4*)&sm.p1.h[r][kb];
          acc[r] += wU[kb]*v.x + wU[kb+1]*v.y + wU[kb+2]*v.z + wU[kb+3]*v.w;
        }
      }
#pragma unroll
      for (int r = 0; r < M; ++r) sm.p1.g[r][tid] = acc[r];
    }
    __syncthreads();

    // ---- LSTM pointwise + store H + stage x_{t+1} ----
    for (int idx = tid; idx < M*HH; idx += NT){
      int r = idx >> 7, j = idx & 127;
      float iv = sigf (sm.p1.g[r][j]);
      float fv = sigf (sm.p1.g[r][j +   HH]);
      float gv = tanhx(sm.p1.g[r][j + 2*HH]);
      float ov = sigf (sm.p1.g[r][j + 3*HH]);
      float cn = fv * sm.p1.c[r][j] + iv * gv;
      float hn = ov * tanhx(cn);
      sm.p1.c[r][j] = cn; sm.p1.h[r][j] = hn;
      Hws[(size_t)(b0+r)*SS*HH + (size_t)t*HH + j] = hn;
    }
    if (t + 1 < SS){
      int r = tid >> 6, d = tid & 63;
      sm.p1.x[r][d] = X[(size_t)(b0+r)*SS*DD + (size_t)(t+1)*DD + d];
    }
    __syncthreads();
  }

  // ================= Phase 2: betas + h_att (overwrites H in-place) =================
  for (int r = 0; r < M; ++r){
    float* Hrow = Hws + (size_t)(b0+r)*SS*HH;
    const int c  = tid & 127;
    const int th = tid >> 7;   // 0..3, owns rows th*8..th*8+7 of each 32-row chunk
    float hacc[32];
#pragma unroll
    for (int i = 0; i < 32; ++i) hacc[i] = 0.f;

#pragma unroll
    for (int ch = 0; ch < 4; ++ch){
      for (int idx = tid; idx < 32*HH/4; idx += NT)
        ((float4*)sm.p2.A)[idx] = ((const float4*)(Hrow + (size_t)ch*32*HH))[idx];
      __syncthreads();

      { // GEMM1: tmp = tanh(A @ taWa + taba)
        float acc[8];
        const float bv = taba[c];
#pragma unroll
        for (int i = 0; i < 8; ++i) acc[i] = bv;
        for (int k = 0; k < HH; k += 4){
          const float* wp = taWa + (size_t)k*SS + c;
          float w0 = wp[0], w1 = wp[SS], w2 = wp[2*SS], w3 = wp[3*SS];
#pragma unroll
          for (int i = 0; i < 8; ++i){
            float4 v = *(const float4*)&sm.p2.A[th*8+i][k];
            acc[i] += w0*v.x + w1*v.y + w2*v.z + w3*v.w;
          }
        }
#pragma unroll
        for (int i = 0; i < 8; ++i) sm.p2.tmp[th*8+i][c] = tanhx(acc[i]);
      }
      __syncthreads();

      { // GEMM2: bp = tmp @ taVa
        float acc[8];
#pragma unroll
        for (int i = 0; i < 8; ++i) acc[i] = 0.f;
        for (int k = 0; k < SS; k += 4){
          const float* wp = taVa + (size_t)k*SS + c;
          float w0 = wp[0], w1 = wp[SS], w2 = wp[2*SS], w3 = wp[3*SS];
#pragma unroll
          for (int i = 0; i < 8; ++i){
            float4 v = *(const float4*)&sm.p2.tmp[th*8+i][k];
            acc[i] += w0*v.x + w1*v.y + w2*v.z + w3*v.w;
          }
        }
#pragma unroll
        for (int i = 0; i < 8; ++i) sm.p2.bp[th*8+i][c] = acc[i];
      }
      __syncthreads();

      { // softmax rows -> beta ; write betas ; keep beta in LDS
        const int wv = tid >> 6, lane = tid & 63;
#pragma unroll
        for (int it = 0; it < 4; ++it){
          int tl = wv + 8*it;
          float v0 = sm.p2.bp[tl][lane], v1 = sm.p2.bp[tl][lane+64];
          float mm = wmax64(fmaxf(v0, v1));
          float e0 = __expf(v0 - mm), e1 = __expf(v1 - mm);
          float inv = 1.0f / wsum64(e0 + e1);
          e0 *= inv; e1 *= inv;
          size_t bo = BETA_OFF + (size_t)(ch*32+tl)*BB*SS + (size_t)(b0+r)*SS;
          out[bo + lane]      = e0;
          out[bo + lane + 64] = e1;
          sm.p2.bp[tl][lane]      = e0;
          sm.p2.bp[tl][lane + 64] = e1;
        }
      }
      __syncthreads();

      // GEMM3: h_att(chunk rows) += beta @ Hrow
      for (int k = 0; k < SS; k += 4){
        const float* hp = Hrow + (size_t)k*HH + c;
        float hv0 = hp[0], hv1 = hp[HH], hv2 = hp[2*HH], hv3 = hp[3*HH];
#pragma unroll
        for (int i = 0; i < 8; ++i){
          float4 bv = *(const float4*)&sm.p2.bp[th*8+i][k];
          hacc[ch*8+i] += bv.x*hv0 + bv.y*hv1 + bv.z*hv2 + bv.w*hv3;
        }
      }
    }
    __syncthreads();
#pragma unroll
    for (int ch = 0; ch < 4; ++ch)
#pragma unroll
      for (int i = 0; i < 8; ++i)
        Hrow[(size_t)(ch*32 + th*8 + i)*HH + c] = hacc[ch*8+i];
    __syncthreads();
  }
}

// ============ Kernel B: G0[b,t,:] = h_att[b,t,:] @ ta_W + ta_b ============
#define BROWS 32
#define NTB 512
__global__ __launch_bounds__(NTB, 2) void g0_kernel(
    const float* __restrict__ Ha, const float* __restrict__ taW,
    const float* __restrict__ tab, float* __restrict__ G0)
{
  __shared__ float hs[BROWS][HH];   // 16 KB
  const int tid = threadIdx.x;
  const size_t row0 = (size_t)blockIdx.x * BROWS;
  for (int idx = tid; idx < BROWS*HH/4; idx += NTB)
    ((float4*)hs)[idx] = ((const float4*)(Ha + row0*HH))[idx];
  __syncthreads();
  const int c = tid;
  float acc[BROWS];
  const float tb = tab[c];
#pragma unroll
  for (int r = 0; r < BROWS; ++r) acc[r] = tb;
  for (int k = 0; k < HH; k += 4){
    const float* wp = taW + (size_t)k*NG + c;
    float w0 = wp[0], w1 = wp[NG], w2 = wp[2*NG], w3 = wp[3*NG];
#pragma unroll
    for (int r = 0; r < BROWS; ++r){
      float4 v = *(const float4*)&hs[r][k];
      acc[r] += w0*v.x + w1*v.y + w2*v.z + w3*v.w;
    }
  }
#pragma unroll
  for (int r = 0; r < BROWS; ++r) G0[(row0 + r)*NG + c] = acc[r];
}

// ============ Kernel C: temporal LSTM (taU weight-stationary) ============
template<int UG>
__global__ __launch_bounds__(NT) __attribute__((amdgpu_waves_per_eu(2, 2)))
void sta_ph3_kernel(
    const float* __restrict__ X, const float* __restrict__ Ha,
    const float* __restrict__ G0,
    const float* __restrict__ taW, const float* __restrict__ taU,
    const float* __restrict__ tab, const float* __restrict__ taWy,
    const float* __restrict__ fcw, const float* __restrict__ fcb,
    float* __restrict__ out)
{
  __shared__ struct {
    float ha[M][HH];
    float lh[M][HH];
    float lc[M][HH];
    float g[M][NG];
    float yp[M];
  } s;
  const int tid = threadIdx.x;
  const int b0  = blockIdx.x * M;

  float wUU[HH];                       // taU[:,tid] in registers
#pragma unroll
  for (int k = 0; k < HH; ++k) wUU[k] = taU[(size_t)k*NG + tid];
  const float wy = taWy[tid];
  const float tb = tab[tid];

  for (int idx = tid; idx < M*HH; idx += NT){
    int r = idx >> 7, j = idx & 127;
    s.lh[r][j] = 0.f; s.lc[r][j] = 0.f;
  }
  if (tid < M) s.yp[tid] = X[(size_t)(b0+tid)*SS*DD + (DD-1)];
  if (!UG && tid < M*HH/4){
    int r = tid >> 5, q = tid & 31;
    ((float4*)s.ha)[tid] = *(const float4*)(Ha + (size_t)(b0+r)*SS*HH + q*4);
  }
  __syncthreads();

  for (int t = 0; t < SS; ++t){
    // ---- gates ----
    {
      float ext[M];
      if (UG){
#pragma unroll
        for (int r = 0; r < M; ++r)
          ext[r] = G0[((size_t)(b0+r)*SS + t)*NG + tid];   // taW part + tab, precomputed
      }
      float acc[M];
#pragma unroll
      for (int r = 0; r < M; ++r) acc[r] = s.yp[r]*wy;
      if (!UG){
#pragma unroll
        for (int r = 0; r < M; ++r) acc[r] += tb;
        for (int kb = 0; kb < HH; kb += 4){
          const float* wp = taW + (size_t)kb*NG + tid;
          float a0 = wp[0], a1 = wp[NG], a2 = wp[2*NG], a3 = wp[3*NG];
#pragma unroll
          for (int r = 0; r < M; ++r){
            float4 v = *(const float4*)&s.ha[r][kb];
            acc[r] += a0*v.x + a1*v.y + a2*v.z + a3*v.w;
          }
        }
      }
#pragma unroll
      for (int kb = 0; kb < HH; kb += 4){
#pragma unroll
        for (int r = 0; r < M; ++r){
          float4 v = *(const float4*)&s.lh[r][kb];
          acc[r] += wUU[kb]*v.x + wUU[kb+1]*v.y + wUU[kb+2]*v.z + wUU[kb+3]*v.w;
        }
      }
      if (UG){
#pragma unroll
        for (int r = 0; r < M; ++r) acc[r] += ext[r];
      }
#pragma unroll
      for (int r = 0; r < M; ++r) s.g[r][tid] = acc[r];
    }
    __syncthreads();

    // ---- pointwise + (fallback) stage ha(t+1) ----
    for (int idx = tid; idx < M*HH; idx += NT){
      int r = idx >> 7, j = idx & 127;
      float iv = sigf (s.g[r][j]);
      float fv = sigf (s.g[r][j +   HH]);
      float gv = tanhx(s.g[r][j + 2*HH]);
      float ov = sigf (s.g[r][j + 3*HH]);
      float cn = fv * s.lc[r][j] + iv * gv;
      float hn = ov * tanhx(cn);
      s.lc[r][j] = cn; s.lh[r][j] = hn;
    }
    if (!UG && t + 1 < SS && tid < M*HH/4){
      int r = tid >> 5, q = tid & 31;
      ((float4*)s.ha)[tid] =
        *(const float4*)(Ha + (size_t)(b0+r)*SS*HH + (size_t)(t+1)*HH + q*4);
    }
    __syncthreads();

    // ---- y = lh @ fc_w^T + fc_b (wave r, 64 lanes) ----
    {
      const int r = tid >> 6, l = tid & 63;
      float p = s.lh[r][l] * fcw[l] + s.lh[r][l+64] * fcw[l+64];
      p = wsum64(p);
      if (l == 0) s.yp[r] = p + fcb[0];
    }
    __syncthreads();
  }

  if (tid < M) out[b0 + tid] = s.yp[tid];
}

extern "C" void kernel_launch(void* const* d_in, const int* in_sizes, int n_in,
                              void* d_out, int out_size, void* d_ws, size_t ws_size,
                              hipStream_t stream) {
  (void)in_sizes; (void)n_in; (void)out_size;
  const float* X    = (const float*)d_in[0];
  const float* saW  = (const float*)d_in[1];
  const float* saU  = (const float*)d_in[2];
  const float* sab  = (const float*)d_in[3];
  const float* saWa = (const float*)d_in[4];
  const float* saUa = (const float*)d_in[5];
  const float* saba = (const float*)d_in[6];
  const float* saVa = (const float*)d_in[7];
  const float* taWa = (const float*)d_in[8];
  // d_in[9] = ta_Ua: unused by the reference forward pass
  const float* taba = (const float*)d_in[10];
  const float* taVa = (const float*)d_in[11];
  const float* taW  = (const float*)d_in[12];
  const float* taU  = (const float*)d_in[13];
  const float* tab  = (const float*)d_in[14];
  const float* taWy = (const float*)d_in[15];
  const float* fcw  = (const float*)d_in[16];
  const float* fcb  = (const float*)d_in[17];
  float* out = (float*)d_out;
  float* Hws = (float*)d_ws;                       // B*S*H floats: H, then h_att
  float* G0  = Hws + (size_t)BB*SS*HH;             // B*S*4H2 floats (if ws allows)
  const bool useG0 = ws_size >= (H_BYTES + G0_BYTES);

  hipLaunchKernelGGL(sta_ph12_kernel, dim3(BB / M), dim3(NT), 0, stream,
                     X, saW, saU, sab, saWa, saUa, saba, saVa,
                     taWa, taba, taVa, out, Hws);
  if (useG0){
    hipLaunchKernelGGL(g0_kernel, dim3((BB*SS)/BROWS), dim3(NTB), 0, stream,
                       Hws, taW, tab, G0);
    hipLaunchKernelGGL((sta_ph3_kernel<1>), dim3(BB / M), dim3(NT), 0, stream,
                       X, Hws, G0, taW, taU, tab, taWy, fcw, fcb, out);
  } else {
    hipLaunchKernelGGL((sta_ph3_kernel<0>), dim3(BB / M), dim3(NT), 0, stream,
                       X, Hws, G0, taW, taU, tab, taWy, fcw, fcb, out);
  }
}

// Round 6
// 3218.958 us; speedup vs baseline: 5.2457x; 2.0998x over previous
//
#include <hip/hip_runtime.h>

// STA-LSTM forward: B=2048, S=128, D=64, H1=H2=128, OUT=1
// Round 6: split-bf16 MFMA for the recurrent gate GEMMs.
//   repack_kernel: weights -> B-fragment-ordered split-bf16 in ws (~0.9 MB)
//   mf_ph12 (256 blk x 512 thr, 1 blk/CU via 84KB LDS):
//     phase 1: VALU attention (round-3 structure) + MFMA gates (A-frags in LDS,
//              B-frags streamed from L2 in fragment order)
//     phase 2: betas + h_att (round-3 VALU, overwrites H in ws)
//   mf_ph3: temporal LSTM, single K=256 MFMA loop over [lh;ha]@[taU;taW]
//           (G0 hoist kernel deleted). Fallback to round-3 VALU if ws too small.

#define BB 2048
#define SS 128
#define DD 64
#define HH 128
#define NG 512
#define M  8
#define NT 512

#define A_OFF    ((size_t)BB)
#define BETA_OFF ((size_t)BB + (size_t)SS*BB*DD)
#define H_BYTES  ((size_t)BB*SS*HH*4)

// fragment buffer layout in ws (ushort offsets)
#define B1_ELEMS (192*512)
#define B3_ELEMS (256*512)
#define B1H_OFF 0
#define B1L_OFF (B1_ELEMS)
#define B3H_OFF (2*B1_ELEMS)
#define B3L_OFF (2*B1_ELEMS + B3_ELEMS)
#define FRAG_BYTES ((size_t)(2*B1_ELEMS + 2*B3_ELEMS)*2)   // 917504 B
#define NEED_BYTES (FRAG_BYTES + H_BYTES)

typedef float f32x4 __attribute__((ext_vector_type(4)));
typedef __bf16 bf16x8 __attribute__((ext_vector_type(8)));
union FB { uint4 u; bf16x8 v; };
__device__ __forceinline__ bf16x8 as_bf(uint4 u){ FB x; x.u = u; return x.v; }

__device__ __forceinline__ unsigned short bf16rne(float f){
  unsigned u = __float_as_uint(f);
  u = (u + 0x7FFFu + ((u >> 16) & 1u)) >> 16;
  return (unsigned short)u;
}
__device__ __forceinline__ float bfval(unsigned short h){
  return __uint_as_float(((unsigned)h) << 16);
}

__device__ __forceinline__ float sigf(float x){ return 1.0f/(1.0f + __expf(-x)); }
__device__ __forceinline__ float tanhx(float x){ return 1.0f - 2.0f/(1.0f + __expf(2.0f*x)); }

__device__ __forceinline__ float wmax64(float v){
#pragma unroll
  for (int m = 32; m; m >>= 1) v = fmaxf(v, __shfl_xor(v, m, 64));
  return v;
}
__device__ __forceinline__ float wsum64(float v){
#pragma unroll
  for (int m = 32; m; m >>= 1) v += __shfl_xor(v, m, 64);
  return v;
}

// ================= repack: weights -> fragment-ordered split-bf16 =================
// B1: K=192 ([saW;saU]), N=512, 6 k-tiles.  B3: K=256 ([taU;taW]), N=512, 8 k-tiles.
// frag slot: lane=(kw>>3)*16 + (n&15), j=kw&7, tile nt=n>>4, kt=k>>5.
__global__ __launch_bounds__(256) void repack_kernel(
    const float* __restrict__ saW, const float* __restrict__ saU,
    const float* __restrict__ taU, const float* __restrict__ taW,
    unsigned short* __restrict__ F)
{
  int id = blockIdx.x*256 + threadIdx.x;
  if (id < B1_ELEMS){
    int k = id >> 9, n = id & 511;
    float v = (k < DD) ? saW[(size_t)k*NG + n] : saU[(size_t)(k-DD)*NG + n];
    int kt = k >> 5, kw = k & 31, nt = n >> 4, nc = n & 15;
    int lane = ((kw >> 3) << 4) | nc, j = kw & 7;
    size_t off = ((size_t)(nt*6 + kt)*64 + lane)*8 + j;
    unsigned short hi = bf16rne(v);
    unsigned short lo = bf16rne(v - bfval(hi));
    F[B1H_OFF + off] = hi; F[B1L_OFF + off] = lo;
  }
  if (id < B3_ELEMS){
    int k = id >> 9, n = id & 511;
    float v = (k < HH) ? taU[(size_t)k*NG + n] : taW[(size_t)(k-HH)*NG + n];
    int kt = k >> 5, kw = k & 31, nt = n >> 4, nc = n & 15;
    int lane = ((kw >> 3) << 4) | nc, j = kw & 7;
    size_t off = ((size_t)(nt*8 + kt)*64 + lane)*8 + j;
    unsigned short hi = bf16rne(v);
    unsigned short lo = bf16rne(v - bfval(hi));
    F[B3H_OFF + off] = hi; F[B3L_OFF + off] = lo;
  }
}

// ================= mf_ph12: phase 1 (MFMA gates) + phase 2 =================
struct P1 {
  float x[M][DD];      // 2K
  float a[M][DD];      // 2K
  float h[M][HH];      // 4K
  float c[M][HH];      // 4K
  float xw[M][DD];     // 2K
  float g[M][NG];      // 16K
  float red[8][512];   // 16K
  float sbias[NG];     // 2K
  uint4 afh[6*64];     // 6K
  uint4 afl[6*64];     // 6K  -> 60K
};
struct P2 { float A[32][HH]; float tmp[32][SS]; float bp[32][SS]; };  // 48K
union __align__(16) SMA { P1 p1; P2 p2; float pad[21504]; };          // 84K -> 1 blk/CU

__global__ __launch_bounds__(NT, 2) void mf_ph12_kernel(
    const float* __restrict__ X,   const float* __restrict__ sab,
    const float* __restrict__ saWa, const float* __restrict__ saUa,
    const float* __restrict__ saba, const float* __restrict__ saVa,
    const float* __restrict__ taWa, const float* __restrict__ taba,
    const float* __restrict__ taVa,
    const unsigned short* __restrict__ Fr,
    float* __restrict__ out, float* __restrict__ Hws)
{
  __shared__ SMA sm;
  const int tid = threadIdx.x;
  const int b0  = blockIdx.x * M;
  const int w   = tid >> 6, l = tid & 63;

  for (int idx = tid; idx < M*HH; idx += NT){
    int r = idx >> 7, j = idx & 127;
    sm.p1.h[r][j] = 0.f; sm.p1.c[r][j] = 0.f;
  }
  sm.p1.sbias[tid] = sab[tid];
  { int r = tid >> 6, d = tid & 63;
    sm.p1.x[r][d] = X[(size_t)(b0+r)*SS*DD + d]; }
  __syncthreads();

  for (int t = 0; t < SS; ++t){
    // ---- attn GEMM1 partials (wave k-sliced, weights from L2) ----
    {
      float pr[M];
#pragma unroll
      for (int r = 0; r < M; ++r) pr[r] = 0.f;
      { const int kb = w*8;
#pragma unroll
        for (int q = 0; q < 2; ++q){
          const int k = kb + q*4;
          const float* wp = saWa + (size_t)k*DD + l;
          float w0 = wp[0], w1 = wp[DD], w2 = wp[2*DD], w3 = wp[3*DD];
#pragma unroll
          for (int r = 0; r < M; ++r){
            float4 v = *(const float4*)&sm.p1.x[r][k];
            pr[r] += w0*v.x + w1*v.y + w2*v.z + w3*v.w;
          }
        }
      }
      { const int kb = w*16;
#pragma unroll
        for (int q = 0; q < 4; ++q){
          const int k = kb + q*4;
          const float* wp = saUa + (size_t)k*DD + l;
          float w0 = wp[0], w1 = wp[DD], w2 = wp[2*DD], w3 = wp[3*DD];
#pragma unroll
          for (int r = 0; r < M; ++r){
            float4 v = *(const float4*)&sm.p1.h[r][k];
            pr[r] += w0*v.x + w1*v.y + w2*v.z + w3*v.w;
          }
        }
      }
      { const int kb = w*16;
#pragma unroll
        for (int q = 0; q < 4; ++q){
          const int k = kb + q*4;
          const float* wp = saUa + (size_t)(HH + k)*DD + l;
          float w0 = wp[0], w1 = wp[DD], w2 = wp[2*DD], w3 = wp[3*DD];
#pragma unroll
          for (int r = 0; r < M; ++r){
            float4 v = *(const float4*)&sm.p1.c[r][k];
            pr[r] += w0*v.x + w1*v.y + w2*v.z + w3*v.w;
          }
        }
      }
#pragma unroll
      for (int r = 0; r < M; ++r) sm.p1.red[w][r*64 + l] = pr[r];
    }
    __syncthreads();

    // ---- reduce1 + bias + tanh -> a (wave r handles row r) ----
    {
      const int r = w;
      float s = saba[l];
#pragma unroll
      for (int u = 0; u < 8; ++u) s += sm.p1.red[u][r*64 + l];
      sm.p1.a[r][l] = tanhx(s);
    }
    __syncthreads();

    // ---- attn GEMM2 partials: av = a @ saVa ----
    {
      float pr[M];
#pragma unroll
      for (int r = 0; r < M; ++r) pr[r] = 0.f;
      const int kb = w*8;
#pragma unroll
      for (int q = 0; q < 2; ++q){
        const int k = kb + q*4;
        const float* wp = saVa + (size_t)k*DD + l;
        float w0 = wp[0], w1 = wp[DD], w2 = wp[2*DD], w3 = wp[3*DD];
#pragma unroll
        for (int r = 0; r < M; ++r){
          float4 v = *(const float4*)&sm.p1.a[r][k];
          pr[r] += w0*v.x + w1*v.y + w2*v.z + w3*v.w;
        }
      }
#pragma unroll
      for (int r = 0; r < M; ++r) sm.p1.red[w][r*64 + l] = pr[r];
    }
    __syncthreads();

    // ---- reduce2 + softmax + alphas out + xw ----
    {
      const int r = w;
      float s = 0.f;
#pragma unroll
      for (int u = 0; u < 8; ++u) s += sm.p1.red[u][r*64 + l];
      float mm = wmax64(s);
      float e  = __expf(s - mm);
      float al = e * (1.0f / wsum64(e));
      out[A_OFF + (size_t)t*BB*DD + (size_t)(b0+r)*DD + l] = al;
      sm.p1.xw[r][l] = al * sm.p1.x[r][l];
    }
    __syncthreads();

    // ---- A-frag build (split-bf16, 384 thr) + x(t+1) stage (128 thr) ----
    if (tid < 384){
      const int kt = tid >> 6, lf = tid & 63;
      const int row = lf & 15, kg = lf >> 4;
      unsigned hh[4], lw[4];
      if (row < 8){
        const int kb = kt*32 + kg*8;
#pragma unroll
        for (int jp = 0; jp < 4; ++jp){
          int k0 = kb + jp*2;
          float v0 = (k0   < DD) ? sm.p1.xw[row][k0]   : sm.p1.h[row][k0-DD];
          float v1 = (k0+1 < DD) ? sm.p1.xw[row][k0+1] : sm.p1.h[row][k0+1-DD];
          unsigned short h0 = bf16rne(v0), h1 = bf16rne(v1);
          unsigned short l0 = bf16rne(v0 - bfval(h0)), l1 = bf16rne(v1 - bfval(h1));
          hh[jp] = (unsigned)h0 | ((unsigned)h1 << 16);
          lw[jp] = (unsigned)l0 | ((unsigned)l1 << 16);
        }
      } else {
#pragma unroll
        for (int jp = 0; jp < 4; ++jp){ hh[jp] = 0u; lw[jp] = 0u; }
      }
      sm.p1.afh[kt*64 + lf] = make_uint4(hh[0], hh[1], hh[2], hh[3]);
      sm.p1.afl[kt*64 + lf] = make_uint4(lw[0], lw[1], lw[2], lw[3]);
    } else if (t + 1 < SS){
      int q = tid - 384;
      int r = q >> 4, d0 = (q & 15)*4;
      *(float4*)&sm.p1.x[r][d0] =
        *(const float4*)(X + (size_t)(b0+r)*SS*DD + (size_t)(t+1)*DD + d0);
    }
    __syncthreads();

    // ---- MFMA gates: [16x192] @ [192x512], 3-product split-bf16 ----
    {
      f32x4 zero4 = {0.f, 0.f, 0.f, 0.f};
      f32x4 acc[4];
#pragma unroll
      for (int n4 = 0; n4 < 4; ++n4) acc[n4] = zero4;
      const uint4* bh = ((const uint4*)(Fr + B1H_OFF)) + (size_t)(w*4)*6*64 + l;
      const uint4* bl = ((const uint4*)(Fr + B1L_OFF)) + (size_t)(w*4)*6*64 + l;
#pragma unroll
      for (int kt = 0; kt < 6; ++kt){
        bf16x8 vah = as_bf(sm.p1.afh[kt*64 + l]);
        bf16x8 val = as_bf(sm.p1.afl[kt*64 + l]);
#pragma unroll
        for (int n4 = 0; n4 < 4; ++n4){
          bf16x8 vbh = as_bf(bh[(n4*6 + kt)*64]);
          bf16x8 vbl = as_bf(bl[(n4*6 + kt)*64]);
          acc[n4] = __builtin_amdgcn_mfma_f32_16x16x32_bf16(vah, vbh, acc[n4], 0, 0, 0);
          acc[n4] = __builtin_amdgcn_mfma_f32_16x16x32_bf16(val, vbh, acc[n4], 0, 0, 0);
          acc[n4] = __builtin_amdgcn_mfma_f32_16x16x32_bf16(vah, vbl, acc[n4], 0, 0, 0);
        }
      }
      const int row0 = (l >> 4)*4;
      if (row0 < 8){
        const int colb = w*64 + (l & 15);
#pragma unroll
        for (int n4 = 0; n4 < 4; ++n4){
          int col = colb + n4*16;
          float b = sm.p1.sbias[col];
#pragma unroll
          for (int j = 0; j < 4; ++j) sm.p1.g[row0+j][col] = acc[n4][j] + b;
        }
      }
    }
    __syncthreads();

    // ---- LSTM pointwise + store H ----
    for (int idx = tid; idx < M*HH; idx += NT){
      int r = idx >> 7, j = idx & 127;
      float iv = sigf (sm.p1.g[r][j]);
      float fv = sigf (sm.p1.g[r][j +   HH]);
      float gv = tanhx(sm.p1.g[r][j + 2*HH]);
      float ov = sigf (sm.p1.g[r][j + 3*HH]);
      float cn = fv * sm.p1.c[r][j] + iv * gv;
      float hn = ov * tanhx(cn);
      sm.p1.c[r][j] = cn; sm.p1.h[r][j] = hn;
      Hws[(size_t)(b0+r)*SS*HH + (size_t)t*HH + j] = hn;
    }
    __syncthreads();
  }

  // ================= Phase 2: betas + h_att (round-3, overwrites H) =================
  for (int r = 0; r < M; ++r){
    float* Hrow = Hws + (size_t)(b0+r)*SS*HH;
    const int c  = tid & 127;
    const int th = tid >> 7;
    float hacc[32];
#pragma unroll
    for (int i = 0; i < 32; ++i) hacc[i] = 0.f;

#pragma unroll
    for (int ch = 0; ch < 4; ++ch){
      for (int idx = tid; idx < 32*HH/4; idx += NT)
        ((float4*)sm.p2.A)[idx] = ((const float4*)(Hrow + (size_t)ch*32*HH))[idx];
      __syncthreads();

      { float acc[8];
        const float bv = taba[c];
#pragma unroll
        for (int i = 0; i < 8; ++i) acc[i] = bv;
        for (int k = 0; k < HH; k += 4){
          const float* wp = taWa + (size_t)k*SS + c;
          float w0 = wp[0], w1 = wp[SS], w2 = wp[2*SS], w3 = wp[3*SS];
#pragma unroll
          for (int i = 0; i < 8; ++i){
            float4 v = *(const float4*)&sm.p2.A[th*8+i][k];
            acc[i] += w0*v.x + w1*v.y + w2*v.z + w3*v.w;
          }
        }
#pragma unroll
        for (int i = 0; i < 8; ++i) sm.p2.tmp[th*8+i][c] = tanhx(acc[i]);
      }
      __syncthreads();

      { float acc[8];
#pragma unroll
        for (int i = 0; i < 8; ++i) acc[i] = 0.f;
        for (int k = 0; k < SS; k += 4){
          const float* wp = taVa + (size_t)k*SS + c;
          float w0 = wp[0], w1 = wp[SS], w2 = wp[2*SS], w3 = wp[3*SS];
#pragma unroll
          for (int i = 0; i < 8; ++i){
            float4 v = *(const float4*)&sm.p2.tmp[th*8+i][k];
            acc[i] += w0*v.x + w1*v.y + w2*v.z + w3*v.w;
          }
        }
#pragma unroll
        for (int i = 0; i < 8; ++i) sm.p2.bp[th*8+i][c] = acc[i];
      }
      __syncthreads();

      { const int wv = tid >> 6, lane = tid & 63;
#pragma unroll
        for (int it = 0; it < 4; ++it){
          int tl = wv + 8*it;
          float v0 = sm.p2.bp[tl][lane], v1 = sm.p2.bp[tl][lane+64];
          float mm = wmax64(fmaxf(v0, v1));
          float e0 = __expf(v0 - mm), e1 = __expf(v1 - mm);
          float inv = 1.0f / wsum64(e0 + e1);
          e0 *= inv; e1 *= inv;
          size_t bo = BETA_OFF + (size_t)(ch*32+tl)*BB*SS + (size_t)(b0+r)*SS;
          out[bo + lane]      = e0;
          out[bo + lane + 64] = e1;
          sm.p2.bp[tl][lane]      = e0;
          sm.p2.bp[tl][lane + 64] = e1;
        }
      }
      __syncthreads();

      for (int k = 0; k < SS; k += 4){
        const float* hp = Hrow + (size_t)k*HH + c;
        float hv0 = hp[0], hv1 = hp[HH], hv2 = hp[2*HH], hv3 = hp[3*HH];
#pragma unroll
        for (int i = 0; i < 8; ++i){
          float4 bv = *(const float4*)&sm.p2.bp[th*8+i][k];
          hacc[ch*8+i] += bv.x*hv0 + bv.y*hv1 + bv.z*hv2 + bv.w*hv3;
        }
      }
    }
    __syncthreads();
#pragma unroll
    for (int ch = 0; ch < 4; ++ch)
#pragma unroll
      for (int i = 0; i < 8; ++i)
        Hrow[(size_t)(ch*32 + th*8 + i)*HH + c] = hacc[ch*8+i];
    __syncthreads();
  }
}

// ================= mf_ph3: temporal LSTM, K=256 MFMA ([lh;ha]@[taU;taW]) =============
struct P3 {
  float ha[2][M][HH];  // 8K (double-buffered)
  float lh[M][HH];     // 4K
  float lc[M][HH];     // 4K
  float g[M][NG];      // 16K
  float sb[NG];        // 2K (tab)
  float wy[NG];        // 2K (taWy)
  float fcv[HH];       // 0.5K
  float yp[M];
  uint4 afh[8*64];     // 8K
  uint4 afl[8*64];     // 8K
};
union __align__(16) SMC { P3 s; float pad[21504]; };   // 84K -> 1 blk/CU

__global__ __launch_bounds__(NT, 2) void mf_ph3_kernel(
    const float* __restrict__ X, const float* __restrict__ Ha,
    const unsigned short* __restrict__ Fr,
    const float* __restrict__ tab, const float* __restrict__ taWy,
    const float* __restrict__ fcw, const float* __restrict__ fcb,
    float* __restrict__ out)
{
  __shared__ SMC sm;
  const int tid = threadIdx.x;
  const int b0  = blockIdx.x * M;
  const int w   = tid >> 6, l = tid & 63;

  for (int idx = tid; idx < M*HH; idx += NT){
    int r = idx >> 7, j = idx & 127;
    sm.s.lh[r][j] = 0.f; sm.s.lc[r][j] = 0.f;
  }
  sm.s.sb[tid] = tab[tid];
  sm.s.wy[tid] = taWy[tid];
  if (tid < HH) sm.s.fcv[tid] = fcw[tid];
  if (tid < M)  sm.s.yp[tid] = X[(size_t)(b0+tid)*SS*DD + (DD-1)];
  if (tid < 256){
    int r = tid >> 5, q = (tid & 31)*4;
    *(float4*)&sm.s.ha[0][r][q] = *(const float4*)(Ha + (size_t)(b0+r)*SS*HH + q);
  }
  __syncthreads();

  for (int t = 0; t < SS; ++t){
    // ---- A-frag build (all 512 thr: 8 kt x 64 lanes) + ha(t+1) prefetch ----
    {
      const float (*haC)[HH] = sm.s.ha[t & 1];
      float4 pf; int pr = 0, pq = 0;
      const bool dop = (t + 1 < SS) && (tid < 256);
      if (dop){
        pr = tid >> 5; pq = (tid & 31)*4;
        pf = *(const float4*)(Ha + (size_t)(b0+pr)*SS*HH + (size_t)(t+1)*HH + pq);
      }
      const int kt = tid >> 6, lf = tid & 63;
      const int row = lf & 15, kg = lf >> 4;
      unsigned hh[4], lw[4];
      if (row < 8){
        const int kb = kt*32 + kg*8;
#pragma unroll
        for (int jp = 0; jp < 4; ++jp){
          int k0 = kb + jp*2;
          float v0 = (k0   < HH) ? sm.s.lh[row][k0]   : haC[row][k0-HH];
          float v1 = (k0+1 < HH) ? sm.s.lh[row][k0+1] : haC[row][k0+1-HH];
          unsigned short h0 = bf16rne(v0), h1 = bf16rne(v1);
          unsigned short l0 = bf16rne(v0 - bfval(h0)), l1 = bf16rne(v1 - bfval(h1));
          hh[jp] = (unsigned)h0 | ((unsigned)h1 << 16);
          lw[jp] = (unsigned)l0 | ((unsigned)l1 << 16);
        }
      } else {
#pragma unroll
        for (int jp = 0; jp < 4; ++jp){ hh[jp] = 0u; lw[jp] = 0u; }
      }
      sm.s.afh[kt*64 + lf] = make_uint4(hh[0], hh[1], hh[2], hh[3]);
      sm.s.afl[kt*64 + lf] = make_uint4(lw[0], lw[1], lw[2], lw[3]);
      if (dop) *(float4*)&sm.s.ha[(t+1) & 1][pr][pq] = pf;
    }
    __syncthreads();

    // ---- MFMA gates: [16x256] @ [256x512] + tab + yp*taWy ----
    {
      f32x4 zero4 = {0.f, 0.f, 0.f, 0.f};
      f32x4 acc[4];
#pragma unroll
      for (int n4 = 0; n4 < 4; ++n4) acc[n4] = zero4;
      const uint4* bh = ((const uint4*)(Fr + B3H_OFF)) + (size_t)(w*4)*8*64 + l;
      const uint4* bl = ((const uint4*)(Fr + B3L_OFF)) + (size_t)(w*4)*8*64 + l;
#pragma unroll
      for (int kt = 0; kt < 8; ++kt){
        bf16x8 vah = as_bf(sm.s.afh[kt*64 + l]);
        bf16x8 val = as_bf(sm.s.afl[kt*64 + l]);
#pragma unroll
        for (int n4 = 0; n4 < 4; ++n4){
          bf16x8 vbh = as_bf(bh[(n4*8 + kt)*64]);
          bf16x8 vbl = as_bf(bl[(n4*8 + kt)*64]);
          acc[n4] = __builtin_amdgcn_mfma_f32_16x16x32_bf16(vah, vbh, acc[n4], 0, 0, 0);
          acc[n4] = __builtin_amdgcn_mfma_f32_16x16x32_bf16(val, vbh, acc[n4], 0, 0, 0);
          acc[n4] = __builtin_amdgcn_mfma_f32_16x16x32_bf16(vah, vbl, acc[n4], 0, 0, 0);
        }
      }
      const int row0 = (l >> 4)*4;
      if (row0 < 8){
        const int colb = w*64 + (l & 15);
#pragma unroll
        for (int n4 = 0; n4 < 4; ++n4){
          int col = colb + n4*16;
          float b = sm.s.sb[col];
          float wv = sm.s.wy[col];
#pragma unroll
          for (int j = 0; j < 4; ++j)
            sm.s.g[row0+j][col] = acc[n4][j] + b + sm.s.yp[row0+j]*wv;
        }
      }
    }
    __syncthreads();

    // ---- LSTM pointwise ----
    for (int idx = tid; idx < M*HH; idx += NT){
      int r = idx >> 7, j = idx & 127;
      float iv = sigf (sm.s.g[r][j]);
      float fv = sigf (sm.s.g[r][j +   HH]);
      float gv = tanhx(sm.s.g[r][j + 2*HH]);
      float ov = sigf (sm.s.g[r][j + 3*HH]);
      float cn = fv * sm.s.lc[r][j] + iv * gv;
      float hn = ov * tanhx(cn);
      sm.s.lc[r][j] = cn; sm.s.lh[r][j] = hn;
    }
    __syncthreads();

    // ---- y = lh @ fc_w^T + fc_b ----
    {
      const int r = tid >> 6, lx = tid & 63;
      float p = sm.s.lh[r][lx]*sm.s.fcv[lx] + sm.s.lh[r][lx+64]*sm.s.fcv[lx+64];
      p = wsum64(p);
      if (lx == 0) sm.s.yp[r] = p + fcb[0];
    }
    __syncthreads();
  }

  if (tid < M) out[b0 + tid] = sm.s.yp[tid];
}

// ================= Fallback (round-3 VALU kernels, if ws too small) ===============
struct FSM1 {
  float x[M][DD]; float h[M][HH]; float c[M][HH];
  float a[M][DD]; float xw[M][DD]; float g[M][NG];
};
struct FP1 { FSM1 s; float red[8][512]; };
union __align__(16) FSMA { FP1 p1; P2 p2; float pad[21504]; };

__global__ __launch_bounds__(NT, 2) void fb_ph12_kernel(
    const float* __restrict__ X,
    const float* __restrict__ saW,  const float* __restrict__ saU,  const float* __restrict__ sab,
    const float* __restrict__ saWa, const float* __restrict__ saUa, const float* __restrict__ saba,
    const float* __restrict__ saVa,
    const float* __restrict__ taWa, const float* __restrict__ taba, const float* __restrict__ taVa,
    float* __restrict__ out, float* __restrict__ Hws)
{
  __shared__ FSMA sm;
  const int tid = threadIdx.x;
  const int b0  = blockIdx.x * M;
  const int w   = tid >> 6, l = tid & 63;

  for (int idx = tid; idx < M*HH; idx += NT){
    int r = idx >> 7, j = idx & 127;
    sm.p1.s.h[r][j] = 0.f; sm.p1.s.c[r][j] = 0.f;
  }
  { int r = tid >> 6, d = tid & 63;
    sm.p1.s.x[r][d] = X[(size_t)(b0+r)*SS*DD + d]; }
  __syncthreads();

  for (int t = 0; t < SS; ++t){
    {
      float pr[M];
#pragma unroll
      for (int r = 0; r < M; ++r) pr[r] = 0.f;
      { const int kb = w*8;
#pragma unroll
        for (int q = 0; q < 2; ++q){
          const int k = kb + q*4;
          const float* wp = saWa + (size_t)k*DD + l;
          float w0 = wp[0], w1 = wp[DD], w2 = wp[2*DD], w3 = wp[3*DD];
#pragma unroll
          for (int r = 0; r < M; ++r){
            float4 v = *(const float4*)&sm.p1.s.x[r][k];
            pr[r] += w0*v.x + w1*v.y + w2*v.z + w3*v.w;
          }
        }
      }
      { const int kb = w*16;
#pragma unroll
        for (int q = 0; q < 4; ++q){
          const int k = kb + q*4;
          const float* wp = saUa + (size_t)k*DD + l;
          float w0 = wp[0], w1 = wp[DD], w2 = wp[2*DD], w3 = wp[3*DD];
#pragma unroll
          for (int r = 0; r < M; ++r){
            float4 v = *(const float4*)&sm.p1.s.h[r][k];
            pr[r] += w0*v.x + w1*v.y + w2*v.z + w3*v.w;
          }
        }
      }
      { const int kb = w*16;
#pragma unroll
        for (int q = 0; q < 4; ++q){
          const int k = kb + q*4;
          const float* wp = saUa + (size_t)(HH + k)*DD + l;
          float w0 = wp[0], w1 = wp[DD], w2 = wp[2*DD], w3 = wp[3*DD];
#pragma unroll
          for (int r = 0; r < M; ++r){
            float4 v = *(const float4*)&sm.p1.s.c[r][k];
            pr[r] += w0*v.x + w1*v.y + w2*v.z + w3*v.w;
          }
        }
      }
#pragma unroll
      for (int r = 0; r < M; ++r) sm.p1.red[w][r*64 + l] = pr[r];
    }
    __syncthreads();
    {
      float s = saba[l];
#pragma unroll
      for (int u = 0; u < 8; ++u) s += sm.p1.red[u][w*64 + l];
      sm.p1.s.a[w][l] = tanhx(s);
    }
    __syncthreads();
    {
      float pr[M];
#pragma unroll
      for (int r = 0; r < M; ++r) pr[r] = 0.f;
      const int kb = w*8;
#pragma unroll
      for (int q = 0; q < 2; ++q){
        const int k = kb + q*4;
        const float* wp = saVa + (size_t)k*DD + l;
        float w0 = wp[0], w1 = wp[DD], w2 = wp[2*DD], w3 = wp[3*DD];
#pragma unroll
        for (int r = 0; r < M; ++r){
          float4 v = *(const float4*)&sm.p1.s.a[r][k];
          pr[r] += w0*v.x + w1*v.y + w2*v.z + w3*v.w;
        }
      }
#pragma unroll
      for (int r = 0; r < M; ++r) sm.p1.red[w][r*64 + l] = pr[r];
    }
    __syncthreads();
    {
      float s = 0.f;
#pragma unroll
      for (int u = 0; u < 8; ++u) s += sm.p1.red[u][w*64 + l];
      float mm = wmax64(s);
      float e  = __expf(s - mm);
      float al = e * (1.0f / wsum64(e));
      out[A_OFF + (size_t)t*BB*DD + (size_t)(b0+w)*DD + l] = al;
      sm.p1.s.xw[w][l] = al * sm.p1.s.x[w][l];
    }
    __syncthreads();
    {
      const int c0 = tid;
      float acc[M];
      const float bv = sab[c0];
#pragma unroll
      for (int r = 0; r < M; ++r) acc[r] = bv;
      for (int k = 0; k < DD; k += 4){
        const float* wp = saW + (size_t)k*NG + c0;
        float w0 = wp[0], w1 = wp[NG], w2 = wp[2*NG], w3 = wp[3*NG];
#pragma unroll
        for (int r = 0; r < M; ++r){
          float4 v = *(const float4*)&sm.p1.s.xw[r][k];
          acc[r] += w0*v.x + w1*v.y + w2*v.z + w3*v.w;
        }
      }
      for (int k = 0; k < HH; k += 4){
        const float* wp = saU + (size_t)k*NG + c0;
        float w0 = wp[0], w1 = wp[NG], w2 = wp[2*NG], w3 = wp[3*NG];
#pragma unroll
        for (int r = 0; r < M; ++r){
          float4 v = *(const float4*)&sm.p1.s.h[r][k];
          acc[r] += w0*v.x + w1*v.y + w2*v.z + w3*v.w;
        }
      }
#pragma unroll
      for (int r = 0; r < M; ++r) sm.p1.s.g[r][c0] = acc[r];
    }
    __syncthreads();
    for (int idx = tid; idx < M*HH; idx += NT){
      int r = idx >> 7, j = idx & 127;
      float iv = sigf (sm.p1.s.g[r][j]);
      float fv = sigf (sm.p1.s.g[r][j +   HH]);
      float gv = tanhx(sm.p1.s.g[r][j + 2*HH]);
      float ov = sigf (sm.p1.s.g[r][j + 3*HH]);
      float cn = fv * sm.p1.s.c[r][j] + iv * gv;
      float hn = ov * tanhx(cn);
      sm.p1.s.c[r][j] = cn; sm.p1.s.h[r][j] = hn;
      Hws[(size_t)(b0+r)*SS*HH + (size_t)t*HH + j] = hn;
    }
    if (t + 1 < SS){
      int r = tid >> 6, d = tid & 63;
      sm.p1.s.x[r][d] = X[(size_t)(b0+r)*SS*DD + (size_t)(t+1)*DD + d];
    }
    __syncthreads();
  }

  for (int r = 0; r < M; ++r){
    float* Hrow = Hws + (size_t)(b0+r)*SS*HH;
    const int c  = tid & 127;
    const int th = tid >> 7;
    float hacc[32];
#pragma unroll
    for (int i = 0; i < 32; ++i) hacc[i] = 0.f;
#pragma unroll
    for (int ch = 0; ch < 4; ++ch){
      for (int idx = tid; idx < 32*HH/4; idx += NT)
        ((float4*)sm.p2.A)[idx] = ((const float4*)(Hrow + (size_t)ch*32*HH))[idx];
      __syncthreads();
      { float acc[8];
        const float bv = taba[c];
#pragma unroll
        for (int i = 0; i < 8; ++i) acc[i] = bv;
        for (int k = 0; k < HH; k += 4){
          const float* wp = taWa + (size_t)k*SS + c;
          float w0 = wp[0], w1 = wp[SS], w2 = wp[2*SS], w3 = wp[3*SS];
#pragma unroll
          for (int i = 0; i < 8; ++i){
            float4 v = *(const float4*)&sm.p2.A[th*8+i][k];
            acc[i] += w0*v.x + w1*v.y + w2*v.z + w3*v.w;
          }
        }
#pragma unroll
        for (int i = 0; i < 8; ++i) sm.p2.tmp[th*8+i][c] = tanhx(acc[i]);
      }
      __syncthreads();
      { float acc[8];
#pragma unroll
        for (int i = 0; i < 8; ++i) acc[i] = 0.f;
        for (int k = 0; k < SS; k += 4){
          const float* wp = taVa + (size_t)k*SS + c;
          float w0 = wp[0], w1 = wp[SS], w2 = wp[2*SS], w3 = wp[3*SS];
#pragma unroll
          for (int i = 0; i < 8; ++i){
            float4 v = *(const float4*)&sm.p2.tmp[th*8+i][k];
            acc[i] += w0*v.x + w1*v.y + w2*v.z + w3*v.w;
          }
        }
#pragma unroll
        for (int i = 0; i < 8; ++i) sm.p2.bp[th*8+i][c] = acc[i];
      }
      __syncthreads();
      { const int wv = tid >> 6, lane = tid & 63;
#pragma unroll
        for (int it = 0; it < 4; ++it){
          int tl = wv + 8*it;
          float v0 = sm.p2.bp[tl][lane], v1 = sm.p2.bp[tl][lane+64];
          float mm = wmax64(fmaxf(v0, v1));
          float e0 = __expf(v0 - mm), e1 = __expf(v1 - mm);
          float inv = 1.0f / wsum64(e0 + e1);
          e0 *= inv; e1 *= inv;
          size_t bo = BETA_OFF + (size_t)(ch*32+tl)*BB*SS + (size_t)(b0+r)*SS;
          out[bo + lane]      = e0;
          out[bo + lane + 64] = e1;
          sm.p2.bp[tl][lane]      = e0;
          sm.p2.bp[tl][lane + 64] = e1;
        }
      }
      __syncthreads();
      for (int k = 0; k < SS; k += 4){
        const float* hp = Hrow + (size_t)k*HH + c;
        float hv0 = hp[0], hv1 = hp[HH], hv2 = hp[2*HH], hv3 = hp[3*HH];
#pragma unroll
        for (int i = 0; i < 8; ++i){
          float4 bv = *(const float4*)&sm.p2.bp[th*8+i][k];
          hacc[ch*8+i] += bv.x*hv0 + bv.y*hv1 + bv.z*hv2 + bv.w*hv3;
        }
      }
    }
    __syncthreads();
#pragma unroll
    for (int ch = 0; ch < 4; ++ch)
#pragma unroll
      for (int i = 0; i < 8; ++i)
        Hrow[(size_t)(ch*32 + th*8 + i)*HH + c] = hacc[ch*8+i];
    __syncthreads();
  }
}

__global__ __launch_bounds__(NT, 2) void fb_ph3_kernel(
    const float* __restrict__ X, const float* __restrict__ Ha,
    const float* __restrict__ taW, const float* __restrict__ taU,
    const float* __restrict__ tab, const float* __restrict__ taWy,
    const float* __restrict__ fcw, const float* __restrict__ fcb,
    float* __restrict__ out)
{
  __shared__ struct {
    float ha[M][HH]; float lh[M][HH]; float lc[M][HH];
    float g[M][NG];  float yp[M];
  } s;
  const int tid = threadIdx.x;
  const int b0  = blockIdx.x * M;

  for (int idx = tid; idx < M*HH; idx += NT){
    int r = idx >> 7, j = idx & 127;
    s.lh[r][j] = 0.f; s.lc[r][j] = 0.f;
  }
  if (tid < M) s.yp[tid] = X[(size_t)(b0+tid)*SS*DD + (DD-1)];
  if (tid < M*HH/4){
    int r = tid >> 5, q = tid & 31;
    ((float4*)s.ha)[tid] = *(const float4*)(Ha + (size_t)(b0+r)*SS*HH + q*4);
  }
  __syncthreads();

  for (int t = 0; t < SS; ++t){
    {
      const int c0 = tid;
      const float wy = taWy[c0];
      const float tb = tab[c0];
      float acc[M];
#pragma unroll
      for (int r = 0; r < M; ++r) acc[r] = tb + s.yp[r]*wy;
      for (int k = 0; k < HH; k += 4){
        const float* wp = taW + (size_t)k*NG + c0;
        float a0 = wp[0], a1 = wp[NG], a2 = wp[2*NG], a3 = wp[3*NG];
#pragma unroll
        for (int r = 0; r < M; ++r){
          float4 v = *(const float4*)&s.ha[r][k];
          acc[r] += a0*v.x + a1*v.y + a2*v.z + a3*v.w;
        }
      }
      for (int k = 0; k < HH; k += 4){
        const float* wp = taU + (size_t)k*NG + c0;
        float a0 = wp[0], a1 = wp[NG], a2 = wp[2*NG], a3 = wp[3*NG];
#pragma unroll
        for (int r = 0; r < M; ++r){
          float4 v = *(const float4*)&s.lh[r][k];
          acc[r] += a0*v.x + a1*v.y + a2*v.z + a3*v.w;
        }
      }
#pragma unroll
      for (int r = 0; r < M; ++r) s.g[r][c0] = acc[r];
    }
    __syncthreads();
    for (int idx = tid; idx < M*HH; idx += NT){
      int r = idx >> 7, j = idx & 127;
      float iv = sigf (s.g[r][j]);
      float fv = sigf (s.g[r][j +   HH]);
      float gv = tanhx(s.g[r][j + 2*HH]);
      float ov = sigf (s.g[r][j + 3*HH]);
      float cn = fv * s.lc[r][j] + iv * gv;
      float hn = ov * tanhx(cn);
      s.lc[r][j] = cn; s.lh[r][j] = hn;
    }
    if (t + 1 < SS && tid < M*HH/4){
      int r = tid >> 5, q = tid & 31;
      ((float4*)s.ha)[tid] =
        *(const float4*)(Ha + (size_t)(b0+r)*SS*HH + (size_t)(t+1)*HH + q*4);
    }
    __syncthreads();
    {
      const int r = tid >> 6, lx = tid & 63;
      float p = s.lh[r][lx]*fcw[lx] + s.lh[r][lx+64]*fcw[lx+64];
      p = wsum64(p);
      if (lx == 0) s.yp[r] = p + fcb[0];
    }
    __syncthreads();
  }
  if (tid < M) out[b0 + tid] = s.yp[tid];
}

extern "C" void kernel_launch(void* const* d_in, const int* in_sizes, int n_in,
                              void* d_out, int out_size, void* d_ws, size_t ws_size,
                              hipStream_t stream) {
  (void)in_sizes; (void)n_in; (void)out_size;
  const float* X    = (const float*)d_in[0];
  const float* saW  = (const float*)d_in[1];
  const float* saU  = (const float*)d_in[2];
  const float* sab  = (const float*)d_in[3];
  const float* saWa = (const float*)d_in[4];
  const float* saUa = (const float*)d_in[5];
  const float* saba = (const float*)d_in[6];
  const float* saVa = (const float*)d_in[7];
  const float* taWa = (const float*)d_in[8];
  // d_in[9] = ta_Ua: unused by the reference forward pass
  const float* taba = (const float*)d_in[10];
  const float* taVa = (const float*)d_in[11];
  const float* taW  = (const float*)d_in[12];
  const float* taU  = (const float*)d_in[13];
  const float* tab  = (const float*)d_in[14];
  const float* taWy = (const float*)d_in[15];
  const float* fcw  = (const float*)d_in[16];
  const float* fcb  = (const float*)d_in[17];
  float* out = (float*)d_out;

  if (ws_size >= NEED_BYTES){
    unsigned short* Fr = (unsigned short*)d_ws;
    float* Hws = (float*)((char*)d_ws + FRAG_BYTES);
    hipLaunchKernelGGL(repack_kernel, dim3(512), dim3(256), 0, stream,
                       saW, saU, taU, taW, Fr);
    hipLaunchKernelGGL(mf_ph12_kernel, dim3(BB / M), dim3(NT), 0, stream,
                       X, sab, saWa, saUa, saba, saVa, taWa, taba, taVa,
                       Fr, out, Hws);
    hipLaunchKernelGGL(mf_ph3_kernel, dim3(BB / M), dim3(NT), 0, stream,
                       X, Hws, Fr, tab, taWy, fcw, fcb, out);
  } else {
    float* Hws = (float*)d_ws;
    hipLaunchKernelGGL(fb_ph12_kernel, dim3(BB / M), dim3(NT), 0, stream,
                       X, saW, saU, sab, saWa, saUa, saba, saVa,
                       taWa, taba, taVa, out, Hws);
    hipLaunchKernelGGL(fb_ph3_kernel, dim3(BB / M), dim3(NT), 0, stream,
                       X, Hws, taW, taU, tab, taWy, fcw, fcb, out);
  }
}